// Round 4
// baseline (697.786 us; speedup 1.0000x reference)
//
#include <hip/hip_runtime.h>
#include <math.h>

// TopKPooling: x[32,256,128,128] f32 -> top-64 (sorted desc) over flattened
// spatial dims -> out[32,256,64] f32.
//
// One block per (b,c) row of 16384 elements. Exact algorithm:
//  1. 256 threads x 64 regs hold the row (single coalesced HBM pass).
//  2. T0 = k-th largest of the 256 per-thread maxima. Provably <= the row's
//     k-th largest value, so {v >= T0} (>= k elements, ~134 expected for
//     normal data) is a superset of the top-k.
//  3. Rank-select survivors into out[row*k + rank] (ties broken by slot ->
//     unique ranks -> sorted descending output).

constexpr int kRows = 8192;    // B*C
constexpr int kN    = 16384;   // H*W
constexpr int kNT   = 256;     // threads per block
constexpr int kEPT  = kN / kNT;  // 64 elements per thread
constexpr int kCAP  = 4096;    // candidate capacity (expected ~134 used)

__global__ __launch_bounds__(kNT, 4)
void topk_kernel(const float* __restrict__ x, const int* __restrict__ kp,
                 float* __restrict__ out) {
    __shared__ float s_max[kNT];
    __shared__ float s_cand[kCAP];
    __shared__ int   s_cnt;
    __shared__ float s_T0;

    const int tid = threadIdx.x;
    const int row = blockIdx.x;
    const int k   = *kp;                       // = 64 (runtime, from device)
    const float* rowp = x + (size_t)row * kN;

    if (tid == 0) s_cnt = 0;

    // --- 1. load 64 elements/thread, fully coalesced float4 ---
    float v[kEPT];
#pragma unroll
    for (int i = 0; i < kEPT / 4; ++i) {
        float4 f = *reinterpret_cast<const float4*>(rowp + i * (kNT * 4) + tid * 4);
        v[4 * i + 0] = f.x;
        v[4 * i + 1] = f.y;
        v[4 * i + 2] = f.z;
        v[4 * i + 3] = f.w;
    }

    // --- 2. per-thread max ---
    float m = v[0];
#pragma unroll
    for (int i = 1; i < kEPT; ++i) m = fmaxf(m, v[i]);
    s_max[tid] = m;
    __syncthreads();

    // rank of m among 256 maxima (descending, tie-break by tid) — broadcast
    // LDS reads (uniform address), no barriers inside the loop
    int rank = 0;
    for (int j = 0; j < kNT; ++j) {
        float mj = s_max[j];
        rank += (mj > m) || (mj == m && j < tid);
    }
    if (rank == k - 1) s_T0 = m;   // exactly one thread (ranks are unique)
    __syncthreads();
    const float T0 = s_T0;

    // --- 3. compact all v >= T0 (superset of top-k, >= k elements) ---
#pragma unroll
    for (int i = 0; i < kEPT; ++i) {
        if (v[i] >= T0) {
            int idx = atomicAdd(&s_cnt, 1);
            if (idx < kCAP) s_cand[idx] = v[i];
        }
    }
    __syncthreads();
    int cnt = s_cnt;
    if (cnt > kCAP) cnt = kCAP;

    // --- 4. rank-select survivors straight into the output row ---
    float* orow = out + (size_t)row * k;
    for (int i = tid; i < cnt; i += kNT) {
        float val = s_cand[i];
        int r = 0;
        for (int j = 0; j < cnt; ++j) {
            float cj = s_cand[j];
            r += (cj > val) || (cj == val && j < i);
        }
        if (r < k) orow[r] = val;
    }
}

extern "C" void kernel_launch(void* const* d_in, const int* in_sizes, int n_in,
                              void* d_out, int out_size, void* d_ws, size_t ws_size,
                              hipStream_t stream) {
    const float* x  = (const float*)d_in[0];
    const int*   kp = (const int*)d_in[1];
    float*       out = (float*)d_out;
    topk_kernel<<<dim3(kRows), dim3(kNT), 0, stream>>>(x, kp, out);
}